// Round 1
// baseline (1897.878 us; speedup 1.0000x reference)
//
#include <hip/hip_runtime.h>
#include <stdint.h>

typedef unsigned short u16;
typedef uint32_t u32;
typedef __attribute__((ext_vector_type(8))) short short8;
typedef __attribute__((ext_vector_type(4))) float f32x4;

#define T_TOK 4096
#define H_DIM 2048
#define E_NUM 32
#define I_DIM 1024
#define IS_DIM 2048
#define TOPK 8
#define NGRP 8
#define TOPG 4
#define EPG (E_NUM / NGRP)
#define RSCALE 2.5f
#define NPAIR (T_TOK * TOPK)

// ---------- helpers ----------

__device__ __forceinline__ u16 f2bf(float f) {
  uint32_t x = __float_as_uint(f);
  uint32_t r = (x + 0x7fffu + ((x >> 16) & 1u)) >> 16;  // RNE
  return (u16)r;
}

__device__ __forceinline__ void gll16(const void* g, void* l) {
  __builtin_amdgcn_global_load_lds(
      (const __attribute__((address_space(1))) void*)g,
      (__attribute__((address_space(3))) void*)l, 16, 0, 0);
}

// ---------- fp32 -> bf16 conversion ----------

__global__ void cvt_kernel(const float* __restrict__ in, u16* __restrict__ out, int n4) {
  int i = blockIdx.x * blockDim.x + threadIdx.x;
  int stride = gridDim.x * blockDim.x;
  for (; i < n4; i += stride) {
    float4 v = reinterpret_cast<const float4*>(in)[i];
    ushort4 o;
    o.x = f2bf(v.x); o.y = f2bf(v.y); o.z = f2bf(v.z); o.w = f2bf(v.w);
    reinterpret_cast<ushort4*>(out)[i] = o;
  }
}

// ---------- router: logits = x @ gate_w.T (fp64 accumulate for exact top-k) ----------

__global__ __launch_bounds__(256) void router_kernel(const float* __restrict__ x,
                                                     const float* __restrict__ gw,
                                                     float* __restrict__ logits) {
  __shared__ float xs[H_DIM];
  int t = blockIdx.x;
  const float* xr = x + (long)t * H_DIM;
  for (int k = threadIdx.x; k < H_DIM; k += 256) xs[k] = xr[k];
  __syncthreads();
  int e = threadIdx.x >> 3;
  int j = threadIdx.x & 7;
  const float* w = gw + (long)e * H_DIM;
  double acc = 0.0;
  for (int k = j; k < H_DIM; k += 8) acc += (double)xs[k] * (double)w[k];
  acc += __shfl_down(acc, 4, 8);
  acc += __shfl_down(acc, 2, 8);
  acc += __shfl_down(acc, 1, 8);
  if (j == 0) logits[t * E_NUM + e] = (float)acc;
}

// ---------- per-token routing ----------

__global__ void zero_kernel(int* counts) {
  int i = threadIdx.x;
  if (i < E_NUM) counts[i] = 0;
}

__global__ void routing_kernel(const float* __restrict__ logits,
                               const float* __restrict__ ebias,
                               int* __restrict__ tk_idx, float* __restrict__ tk_w,
                               int* __restrict__ counts) {
  int t = blockIdx.x * blockDim.x + threadIdx.x;
  if (t >= T_TOK) return;
  float sc[E_NUM], swb[E_NUM];
  for (int e = 0; e < E_NUM; e++) {
    float l = logits[t * E_NUM + e];
    float s = 1.0f / (1.0f + expf(-l));
    sc[e] = s;
    swb[e] = s + ebias[e];
  }
  float gs[NGRP];
  for (int g = 0; g < NGRP; g++) {
    float m1 = -3e38f, m2 = -3e38f;
    for (int i = 0; i < EPG; i++) {
      float v = swb[g * EPG + i];
      if (v > m1) { m2 = m1; m1 = v; }
      else if (v > m2) { m2 = v; }
    }
    gs[g] = m1 + m2;
  }
  bool gmask[NGRP];
  for (int g = 0; g < NGRP; g++) gmask[g] = false;
  for (int k = 0; k < TOPG; k++) {
    int best = 0; float bv = -3e38f;
    for (int g = 0; g < NGRP; g++)
      if (!gmask[g] && gs[g] > bv) { bv = gs[g]; best = g; }
    gmask[best] = true;
  }
  bool taken[E_NUM];
  for (int e = 0; e < E_NUM; e++) taken[e] = false;
  int idx[TOPK]; float wv[TOPK]; float wsum = 0.0f;
  for (int k = 0; k < TOPK; k++) {
    int best = 0; float bv = -3e38f;
    for (int e = 0; e < E_NUM; e++) {
      if (taken[e] || !gmask[e / EPG]) continue;
      if (swb[e] > bv) { bv = swb[e]; best = e; }
    }
    taken[best] = true;
    idx[k] = best;
    wv[k] = sc[best];
    wsum += sc[best];
  }
  float inv = RSCALE / (wsum + 1e-20f);
  for (int k = 0; k < TOPK; k++) {
    tk_idx[t * TOPK + k] = idx[k];
    tk_w[t * TOPK + k] = wv[k] * inv;
    atomicAdd(&counts[idx[k]], 1);
  }
}

__global__ void scan_kernel(const int* __restrict__ counts, int* __restrict__ offsets,
                            int* __restrict__ cursor) {
  if (threadIdx.x == 0 && blockIdx.x == 0) {
    int acc = 0;
    for (int e = 0; e < E_NUM; e++) {
      offsets[e] = acc;
      cursor[e] = acc;
      acc += counts[e];
    }
    offsets[E_NUM] = acc;
  }
}

__global__ void scatter_kernel(const int* __restrict__ tk_idx, const float* __restrict__ tk_w,
                               int* __restrict__ cursor, int* __restrict__ pair_tok,
                               float* __restrict__ pair_w) {
  int t = blockIdx.x * blockDim.x + threadIdx.x;
  if (t >= T_TOK) return;
  for (int k = 0; k < TOPK; k++) {
    int e = tk_idx[t * TOPK + k];
    int p = atomicAdd(&cursor[e], 1);
    pair_tok[p] = t;
    pair_w[p] = tk_w[t * TOPK + k];
  }
}

// ---------- 8-phase GEMM building blocks ----------
// LDS tiles: [rows][64] bf16, 16B-unit XOR swizzle: unit (row, cu) holds logical
// (row, cu ^ (row&7)). Staged linearly by global_load_lds with pre-swizzled
// global source column; read with the same XOR.

__device__ __forceinline__ void rdA4(short8 (&d)[4][2], const u16* s, int arow, int mib,
                                     int pc0, int pc1) {
#pragma unroll
  for (int i = 0; i < 4; ++i) {
    const u16* r = s + arow + (mib + i) * 1024;
    d[i][0] = *(const short8*)(r + pc0);
    d[i][1] = *(const short8*)(r + pc1);
  }
}

__device__ __forceinline__ void rdB2(short8 (&d)[2][2], const u16* s, int brow, int nib,
                                     int pc0, int pc1) {
#pragma unroll
  for (int i = 0; i < 2; ++i) {
    const u16* r = s + brow + (nib + i) * 1024;
    d[i][0] = *(const short8*)(r + pc0);
    d[i][1] = *(const short8*)(r + pc1);
  }
}

__device__ __forceinline__ void mmA(f32x4 (&acc)[8][2], int mib, const short8 (&a)[4][2],
                                    const short8 (&b)[2][2]) {
#pragma unroll
  for (int kk = 0; kk < 2; ++kk)
#pragma unroll
    for (int mi = 0; mi < 4; ++mi)
#pragma unroll
      for (int ni = 0; ni < 2; ++ni)
        acc[mib + mi][ni] =
            __builtin_amdgcn_mfma_f32_16x16x32_bf16(a[mi][kk], b[ni][kk], acc[mib + mi][ni], 0, 0, 0);
}

__device__ __forceinline__ void mmB(f32x4 (&acc)[8][4], int mib, int nib,
                                    const short8 (&a)[4][2], const short8 (&b)[2][2]) {
#pragma unroll
  for (int kk = 0; kk < 2; ++kk)
#pragma unroll
    for (int mi = 0; mi < 4; ++mi)
#pragma unroll
      for (int ni = 0; ni < 2; ++ni)
        acc[mib + mi][nib + ni] =
            __builtin_amdgcn_mfma_f32_16x16x32_bf16(a[mi][kk], b[ni][kk], acc[mib + mi][nib + ni], 0, 0, 0);
}

#define PH_PRE do { \
  __builtin_amdgcn_s_barrier(); \
  asm volatile("s_waitcnt lgkmcnt(0)" ::: "memory"); \
  __builtin_amdgcn_sched_barrier(0); \
  __builtin_amdgcn_s_setprio(1); } while (0)

#define PH_POST do { \
  __builtin_amdgcn_s_setprio(0); \
  __builtin_amdgcn_sched_barrier(0); \
  __builtin_amdgcn_s_barrier(); } while (0)

#define PH_POST_V do { \
  __builtin_amdgcn_s_setprio(0); \
  __builtin_amdgcn_sched_barrier(0); \
  asm volatile("s_waitcnt vmcnt(4)" ::: "memory"); \
  __builtin_amdgcn_s_barrier(); } while (0)

#define STG2(ptr, o0, o1, kt, l0, l1) do { \
  gll16((const void*)((ptr) + (o0) + ((u32)(kt) << 6)), (void*)(l0)); \
  gll16((const void*)((ptr) + (o1) + ((u32)(kt) << 6)), (void*)(l1)); } while (0)

__device__ __forceinline__ void xcd_remap(int& bx, int& by, int& bz) {
  int gx = gridDim.x, gy = gridDim.y;
  int nwg = gx * gy * (int)gridDim.z;  // all launches: nwg % 8 == 0
  int orig = blockIdx.x + gx * (blockIdx.y + gy * blockIdx.z);
  int q8 = nwg >> 3;
  int wg = (orig & 7) * q8 + (orig >> 3);
  bx = wg % gx;
  wg /= gx;
  by = wg % gy;
  bz = wg / gy;
}

// ---------- GEMM1: h = silu(X@W1^T) * (X@W3^T), BM=256, BN=128, dual-B, 8-phase ----------

__global__ __launch_bounds__(512, 2) void gemm1_8p(
    const u16* __restrict__ X, const u16* __restrict__ W1, const u16* __restrict__ W3,
    u16* __restrict__ Hout, const int* __restrict__ rowidx, const int* __restrict__ offsets,
    const int* __restrict__ counts, int K, int N, int Mfixed, long wstride) {
  int bx, by, bz;
  xcd_remap(bx, by, bz);
  int e = bz;
  int base = 0, M = Mfixed;
  if (counts) { M = counts[e]; base = offsets[e]; }
  int m0 = by * 256;
  if (m0 >= M) return;
  int n0 = bx * 128;
  const u16* w1 = W1 + (long)e * wstride;
  const u16* w3 = W3 + (long)e * wstride;

  __shared__ __attribute__((aligned(16))) u16 sA[2][16384];   // 256x64 x2
  __shared__ __attribute__((aligned(16))) u16 sB1[2][8192];   // 128x64 x2
  __shared__ __attribute__((aligned(16))) u16 sB2[2][8192];

  int tid = threadIdx.x;
  int lane = tid & 63, wid = tid >> 6;
  int wm = (wid >> 2) * 128;   // 2 row-waves
  int wn = (wid & 3) * 32;     // 4 col-waves
  int lm = lane & 15, lq = lane >> 4;

  int srow = tid >> 3;                                  // 0..63
  int sc8 = (((tid & 7) ^ (srow & 7)) << 3);            // pre-swizzled source col (elems)

  u32 aOff[4];
#pragma unroll
  for (int j = 0; j < 4; ++j) {
    int r = m0 + srow + j * 64;
    int rr = (r < M) ? r : (M - 1);
    int tok = rowidx ? rowidx[base + rr] : rr;
    aOff[j] = (u32)tok * (u32)K + (u32)sc8;
  }
  u32 bOff[2];
#pragma unroll
  for (int j = 0; j < 2; ++j)
    bOff[j] = (u32)(n0 + srow + j * 64) * (u32)K + (u32)sc8;

  int arow = (wm + lm) * 64;
  int brow = (wn + lm) * 64;
  int x7 = lm & 7;
  int pc0 = ((lq ^ x7) << 3);
  int pc1 = (((4 + lq) ^ x7) << 3);

  f32x4 acc1[8][2] = {};
  f32x4 acc2[8][2] = {};
  short8 aLo[4][2], aHi[4][2], fb1[2][2], fb2[2][2];

  int nt = K >> 6;
  int niter = nt >> 1;

  // prologue: buf0 <- tile0 (A,B1,B2), buf1 <- tile1 (A halves)
  STG2(X, aOff[0], aOff[1], 0, &sA[0][tid * 8], &sA[0][4096 + tid * 8]);
  STG2(X, aOff[2], aOff[3], 0, &sA[0][8192 + tid * 8], &sA[0][12288 + tid * 8]);
  STG2(w1, bOff[0], bOff[1], 0, &sB1[0][tid * 8], &sB1[0][4096 + tid * 8]);
  STG2(w3, bOff[0], bOff[1], 0, &sB2[0][tid * 8], &sB2[0][4096 + tid * 8]);
  STG2(X, aOff[0], aOff[1], 1, &sA[1][tid * 8], &sA[1][4096 + tid * 8]);
  STG2(X, aOff[2], aOff[3], 1, &sA[1][8192 + tid * 8], &sA[1][12288 + tid * 8]);
  asm volatile("s_waitcnt vmcnt(4)" ::: "memory");
  __builtin_amdgcn_s_barrier();

  for (int it = 0; it < niter; ++it) {
    int tb = 2 * it + 1;
    int t2 = 2 * it + 2; if (t2 >= nt) t2 = nt - 1;
    int t3 = 2 * it + 3; if (t3 >= nt) t3 = nt - 1;

    // ph1: buf0 reads aLo,b1; stage buf1.B1(tb)
    rdA4(aLo, sA[0], arow, 0, pc0, pc1);
    rdB2(fb1, sB1[0], brow, 0, pc0, pc1);
    STG2(w1, bOff[0], bOff[1], tb, &sB1[1][tid * 8], &sB1[1][4096 + tid * 8]);
    PH_PRE; mmA(acc1, 0, aLo, fb1); PH_POST;
    // ph2: reads aHi,b2; stage buf1.B2(tb)
    rdA4(aHi, sA[0], arow, 4, pc0, pc1);
    rdB2(fb2, sB2[0], brow, 0, pc0, pc1);
    STG2(w3, bOff[0], bOff[1], tb, &sB2[1][tid * 8], &sB2[1][4096 + tid * 8]);
    PH_PRE; mmA(acc2, 0, aLo, fb2); PH_POST;
    // ph3: re-read b1; stage buf0.Ah0(t2)
    rdB2(fb1, sB1[0], brow, 0, pc0, pc1);
    STG2(X, aOff[0], aOff[1], t2, &sA[0][tid * 8], &sA[0][4096 + tid * 8]);
    PH_PRE; mmA(acc1, 4, aHi, fb1); PH_POST;
    // ph4: stage buf0.Ah1(t2); counted vmcnt
    STG2(X, aOff[2], aOff[3], t2, &sA[0][8192 + tid * 8], &sA[0][12288 + tid * 8]);
    PH_PRE; mmA(acc2, 4, aHi, fb2); PH_POST_V;
    // ph5: buf1 reads aLo,b1; stage buf0.B1(t2)
    rdA4(aLo, sA[1], arow, 0, pc0, pc1);
    rdB2(fb1, sB1[1], brow, 0, pc0, pc1);
    STG2(w1, bOff[0], bOff[1], t2, &sB1[0][tid * 8], &sB1[0][4096 + tid * 8]);
    PH_PRE; mmA(acc1, 0, aLo, fb1); PH_POST;
    // ph6: reads aHi,b2; stage buf0.B2(t2)
    rdA4(aHi, sA[1], arow, 4, pc0, pc1);
    rdB2(fb2, sB2[1], brow, 0, pc0, pc1);
    STG2(w3, bOff[0], bOff[1], t2, &sB2[0][tid * 8], &sB2[0][4096 + tid * 8]);
    PH_PRE; mmA(acc2, 0, aLo, fb2); PH_POST;
    // ph7: re-read b1; stage buf1.Ah0(t3)
    rdB2(fb1, sB1[1], brow, 0, pc0, pc1);
    STG2(X, aOff[0], aOff[1], t3, &sA[1][tid * 8], &sA[1][4096 + tid * 8]);
    PH_PRE; mmA(acc1, 4, aHi, fb1); PH_POST;
    // ph8: stage buf1.Ah1(t3); counted vmcnt
    STG2(X, aOff[2], aOff[3], t3, &sA[1][8192 + tid * 8], &sA[1][12288 + tid * 8]);
    PH_PRE; mmA(acc2, 4, aHi, fb2); PH_POST_V;
  }

  int mrem = M - m0;
#pragma unroll
  for (int mi = 0; mi < 8; ++mi) {
#pragma unroll
    for (int r = 0; r < 4; ++r) {
      int row = wm + mi * 16 + lq * 4 + r;
      if (row >= mrem) continue;
      long orow = (long)(base + m0 + row) * N + n0 + wn + lm;
#pragma unroll
      for (int ni = 0; ni < 2; ++ni) {
        float a = acc1[mi][ni][r];
        float u = acc2[mi][ni][r];
        float hv = (a / (1.0f + __expf(-a))) * u;
        Hout[orow + ni * 16] = f2bf(hv);
      }
    }
  }
}

// ---------- GEMM2: y = Hin @ W2^T, BM=256, BN=256, 8-phase; store or atomic combine ----------

__global__ __launch_bounds__(512, 2) void gemm2_8p(
    const u16* __restrict__ Hin, const u16* __restrict__ W2, float* __restrict__ Out,
    const int* __restrict__ pair_tok, const float* __restrict__ pair_w,
    const int* __restrict__ offsets, const int* __restrict__ counts,
    int K, int N, int Mfixed, long wstride, int atom) {
  int bx, by, bz;
  xcd_remap(bx, by, bz);
  int e = bz;
  int base = 0, M = Mfixed;
  if (counts) { M = counts[e]; base = offsets[e]; }
  int m0 = by * 256;
  if (m0 >= M) return;
  int n0 = bx * 256;
  const u16* w2 = W2 + (long)e * wstride;

  __shared__ __attribute__((aligned(16))) u16 sA[2][16384];   // 256x64 x2
  __shared__ __attribute__((aligned(16))) u16 sB[2][16384];

  int tid = threadIdx.x;
  int lane = tid & 63, wid = tid >> 6;
  int wm = (wid >> 2) * 128;
  int wn = (wid & 3) * 64;
  int lm = lane & 15, lq = lane >> 4;

  int srow = tid >> 3;
  int sc8 = (((tid & 7) ^ (srow & 7)) << 3);

  u32 aOff[4];
#pragma unroll
  for (int j = 0; j < 4; ++j) {
    int r = m0 + srow + j * 64;
    int rr = (r < M) ? r : (M - 1);
    aOff[j] = (u32)(base + rr) * (u32)K + (u32)sc8;
  }
  u32 bOff[4];
#pragma unroll
  for (int j = 0; j < 4; ++j)
    bOff[j] = (u32)(n0 + srow + j * 64) * (u32)K + (u32)sc8;

  int arow = (wm + lm) * 64;
  int brow = (wn + lm) * 64;
  int x7 = lm & 7;
  int pc0 = ((lq ^ x7) << 3);
  int pc1 = (((4 + lq) ^ x7) << 3);

  f32x4 acc[8][4] = {};
  short8 aLo[4][2], aHi[4][2], bLo[2][2], bHi[2][2];

  int nt = K >> 6;
  int niter = nt >> 1;

  STG2(Hin, aOff[0], aOff[1], 0, &sA[0][tid * 8], &sA[0][4096 + tid * 8]);
  STG2(Hin, aOff[2], aOff[3], 0, &sA[0][8192 + tid * 8], &sA[0][12288 + tid * 8]);
  STG2(w2, bOff[0], bOff[1], 0, &sB[0][tid * 8], &sB[0][4096 + tid * 8]);
  STG2(w2, bOff[2], bOff[3], 0, &sB[0][8192 + tid * 8], &sB[0][12288 + tid * 8]);
  STG2(Hin, aOff[0], aOff[1], 1, &sA[1][tid * 8], &sA[1][4096 + tid * 8]);
  STG2(Hin, aOff[2], aOff[3], 1, &sA[1][8192 + tid * 8], &sA[1][12288 + tid * 8]);
  asm volatile("s_waitcnt vmcnt(4)" ::: "memory");
  __builtin_amdgcn_s_barrier();

  for (int it = 0; it < niter; ++it) {
    int tb = 2 * it + 1;
    int t2 = 2 * it + 2; if (t2 >= nt) t2 = nt - 1;
    int t3 = 2 * it + 3; if (t3 >= nt) t3 = nt - 1;

    // ph1
    rdA4(aLo, sA[0], arow, 0, pc0, pc1);
    rdB2(bLo, sB[0], brow, 0, pc0, pc1);
    STG2(w2, bOff[0], bOff[1], tb, &sB[1][tid * 8], &sB[1][4096 + tid * 8]);
    PH_PRE; mmB(acc, 0, 0, aLo, bLo); PH_POST;
    // ph2
    rdA4(aHi, sA[0], arow, 4, pc0, pc1);
    rdB2(bHi, sB[0], brow, 2, pc0, pc1);
    STG2(w2, bOff[2], bOff[3], tb, &sB[1][8192 + tid * 8], &sB[1][12288 + tid * 8]);
    PH_PRE; mmB(acc, 0, 2, aLo, bHi); PH_POST;
    // ph3
    rdB2(bLo, sB[0], brow, 0, pc0, pc1);
    STG2(Hin, aOff[0], aOff[1], t2, &sA[0][tid * 8], &sA[0][4096 + tid * 8]);
    PH_PRE; mmB(acc, 4, 0, aHi, bLo); PH_POST;
    // ph4
    STG2(Hin, aOff[2], aOff[3], t2, &sA[0][8192 + tid * 8], &sA[0][12288 + tid * 8]);
    PH_PRE; mmB(acc, 4, 2, aHi, bHi); PH_POST_V;
    // ph5
    rdA4(aLo, sA[1], arow, 0, pc0, pc1);
    rdB2(bLo, sB[1], brow, 0, pc0, pc1);
    STG2(w2, bOff[0], bOff[1], t2, &sB[0][tid * 8], &sB[0][4096 + tid * 8]);
    PH_PRE; mmB(acc, 0, 0, aLo, bLo); PH_POST;
    // ph6
    rdA4(aHi, sA[1], arow, 4, pc0, pc1);
    rdB2(bHi, sB[1], brow, 2, pc0, pc1);
    STG2(w2, bOff[2], bOff[3], t2, &sB[0][8192 + tid * 8], &sB[0][12288 + tid * 8]);
    PH_PRE; mmB(acc, 0, 2, aLo, bHi); PH_POST;
    // ph7
    rdB2(bLo, sB[1], brow, 0, pc0, pc1);
    STG2(Hin, aOff[0], aOff[1], t3, &sA[1][tid * 8], &sA[1][4096 + tid * 8]);
    PH_PRE; mmB(acc, 4, 0, aHi, bLo); PH_POST;
    // ph8
    STG2(Hin, aOff[2], aOff[3], t3, &sA[1][8192 + tid * 8], &sA[1][12288 + tid * 8]);
    PH_PRE; mmB(acc, 4, 2, aHi, bHi); PH_POST_V;
  }

  int mrem = M - m0;
#pragma unroll
  for (int mi = 0; mi < 8; ++mi) {
#pragma unroll
    for (int r = 0; r < 4; ++r) {
      int row = wm + mi * 16 + lq * 4 + r;
      if (row >= mrem) continue;
      int grow = base + m0 + row;
      int trow;
      float scale;
      if (pair_tok) { trow = pair_tok[grow]; scale = pair_w[grow]; }
      else { trow = grow; scale = 1.0f; }
      long obase = (long)trow * N + n0 + wn + lm;
#pragma unroll
      for (int ni = 0; ni < 4; ++ni) {
        float v = acc[mi][ni][r] * scale;
        if (atom) atomicAdd(&Out[obase + ni * 16], v);
        else Out[obase + ni * 16] = v;
      }
    }
  }
}

// ---------- launch ----------

extern "C" void kernel_launch(void* const* d_in, const int* in_sizes, int n_in, void* d_out,
                              int out_size, void* d_ws, size_t ws_size, hipStream_t stream) {
  const float* x = (const float*)d_in[0];
  const float* gate_w = (const float*)d_in[1];
  const float* e_bias = (const float*)d_in[2];
  const float* w1 = (const float*)d_in[3];
  const float* w3 = (const float*)d_in[4];
  const float* w2 = (const float*)d_in[5];
  const float* sw1 = (const float*)d_in[6];
  const float* sw3 = (const float*)d_in[7];
  const float* sw2 = (const float*)d_in[8];
  float* out = (float*)d_out;

  char* p = (char*)d_ws;
  auto alloc = [&](size_t bytes) {
    char* r = p;
    p += (bytes + 255) & ~(size_t)255;
    return r;
  };
  u16* xb = (u16*)alloc((size_t)T_TOK * H_DIM * 2);
  u16* w1b = (u16*)alloc((size_t)E_NUM * I_DIM * H_DIM * 2);
  u16* w3b = (u16*)alloc((size_t)E_NUM * I_DIM * H_DIM * 2);
  u16* w2b = (u16*)alloc((size_t)E_NUM * H_DIM * I_DIM * 2);
  u16* sw1b = (u16*)alloc((size_t)IS_DIM * H_DIM * 2);
  u16* sw3b = (u16*)alloc((size_t)IS_DIM * H_DIM * 2);
  u16* sw2b = (u16*)alloc((size_t)H_DIM * IS_DIM * 2);
  float* logits = (float*)alloc((size_t)T_TOK * E_NUM * 4);
  int* tk_idx = (int*)alloc((size_t)T_TOK * TOPK * 4);
  float* tk_w = (float*)alloc((size_t)T_TOK * TOPK * 4);
  int* counts = (int*)alloc(256);
  int* offsets = (int*)alloc(256);
  int* cursor = (int*)alloc(256);
  int* pair_tok = (int*)alloc((size_t)NPAIR * 4);
  float* pair_w = (float*)alloc((size_t)NPAIR * 4);
  u16* h_r = (u16*)alloc((size_t)NPAIR * I_DIM * 2);
  u16* h_s = (u16*)alloc((size_t)T_TOK * IS_DIM * 2);

  zero_kernel<<<1, 64, 0, stream>>>(counts);

  cvt_kernel<<<1024, 256, 0, stream>>>(x, xb, T_TOK * H_DIM / 4);
  cvt_kernel<<<4096, 256, 0, stream>>>(w1, w1b, E_NUM * I_DIM * H_DIM / 4);
  cvt_kernel<<<4096, 256, 0, stream>>>(w3, w3b, E_NUM * I_DIM * H_DIM / 4);
  cvt_kernel<<<4096, 256, 0, stream>>>(w2, w2b, E_NUM * H_DIM * I_DIM / 4);
  cvt_kernel<<<512, 256, 0, stream>>>(sw1, sw1b, IS_DIM * H_DIM / 4);
  cvt_kernel<<<512, 256, 0, stream>>>(sw3, sw3b, IS_DIM * H_DIM / 4);
  cvt_kernel<<<512, 256, 0, stream>>>(sw2, sw2b, H_DIM * IS_DIM / 4);

  router_kernel<<<T_TOK, 256, 0, stream>>>(x, gate_w, logits);
  routing_kernel<<<T_TOK / 256, 256, 0, stream>>>(logits, e_bias, tk_idx, tk_w, counts);
  scan_kernel<<<1, 1, 0, stream>>>(counts, offsets, cursor);
  scatter_kernel<<<T_TOK / 256, 256, 0, stream>>>(tk_idx, tk_w, cursor, pair_tok, pair_w);

  // shared MLP: gemm2 store initializes every element of out
  gemm1_8p<<<dim3(IS_DIM / 128, T_TOK / 256, 1), 512, 0, stream>>>(
      xb, sw1b, sw3b, h_s, nullptr, nullptr, nullptr, H_DIM, IS_DIM, T_TOK, 0);
  gemm2_8p<<<dim3(H_DIM / 256, T_TOK / 256, 1), 512, 0, stream>>>(
      h_s, sw2b, out, nullptr, nullptr, nullptr, nullptr, IS_DIM, H_DIM, T_TOK, 0, 0);

  // routed experts: grouped GEMMs over expert-sorted pair list, atomic combine
  gemm1_8p<<<dim3(I_DIM / 128, T_TOK / 256, E_NUM), 512, 0, stream>>>(
      xb, w1b, w3b, h_r, pair_tok, offsets, counts, H_DIM, I_DIM, 0, (long)I_DIM * H_DIM);
  gemm2_8p<<<dim3(H_DIM / 256, T_TOK / 256, E_NUM), 512, 0, stream>>>(
      h_r, w2b, out, pair_tok, pair_w, offsets, counts, I_DIM, H_DIM, 0, (long)H_DIM * I_DIM, 1);
}